// Round 4
// baseline (75.464 us; speedup 1.0000x reference)
//
#include <hip/hip_runtime.h>

// EMA scan: y_t = w*x_t + (1-w)*y_{t-1}, rows = B*C = 8192, T = 4096.
// fp32 in/out. One wave per row; 8 fp32/lane per chunk, 8 chunks per row.
// R4: non-temporal output stores (via clang ext_vector float4 -- HIP's
// float4 struct is rejected by the builtin). Output doesn't allocate in
// L2/L3 -> 134 MB input stays LLC-resident across replays (R2 rocprof
// showed 71 MB avoidable FETCH_SIZE from output evicting input).

#define ROWS 8192
#define T_LEN 4096
#define ITERS 8                // 4096 / 512

typedef float f32x4 __attribute__((ext_vector_type(4)));

__global__ __launch_bounds__(256) void ema_kernel(
    const float* __restrict__ x,     // [ROWS][T_LEN] fp32
    const float* __restrict__ init,  // [ROWS] fp32 (B,C,1 flattened)
    const float* __restrict__ wt,    // [1] fp32
    float* __restrict__ out)         // [ROWS][T_LEN] fp32
{
    const int lane = threadIdx.x & 63;
    const int wid  = threadIdx.x >> 6;
    const int row  = blockIdx.x * 4 + wid;

    float w = wt[0];
    w = fminf(fmaxf(w, 0.0f), 1.0f);
    const float a = 1.0f - w;

    // powers of a: apow[j] = a^j for j=0..8
    float apow[9];
    apow[0] = 1.0f;
    #pragma unroll
    for (int j = 1; j <= 8; ++j) apow[j] = apow[j - 1] * a;
    const float a8  = apow[8];
    const float m1  = a8;        // a^8
    const float m2  = m1 * m1;   // a^16
    const float m4  = m2 * m2;   // a^32
    const float m8  = m4 * m4;   // a^64
    const float m16 = m8 * m8;   // a^128
    const float m32 = m16 * m16; // a^256
    const float a512 = m32 * m32;

    // per-lane power a^(8*lane) via binary exponentiation (branch-free)
    float p8l = 1.0f;
    {
        float b = a8; int e = lane;
        #pragma unroll
        for (int k = 0; k < 6; ++k) {
            p8l *= (e & 1) ? b : 1.0f;
            b *= b; e >>= 1;
        }
    }

    float c = init[row];   // carry y_0

    const f32x4* xrow = reinterpret_cast<const f32x4*>(x) + (size_t)row * (T_LEN / 4);
    f32x4*       orow = reinterpret_cast<f32x4*>(out)     + (size_t)row * (T_LEN / 4);

    // prefetch chunk 0: each lane owns float4 slots (2*lane, 2*lane+1)
    f32x4 va = xrow[2 * lane];
    f32x4 vb = xrow[2 * lane + 1];

    #pragma unroll
    for (int it = 0; it < ITERS; ++it) {
        f32x4 na, nb;
        if (it + 1 < ITERS) {
            na = xrow[(it + 1) * 128 + 2 * lane];
            nb = xrow[(it + 1) * 128 + 2 * lane + 1];
        }

        float xv[8];
        xv[0] = va.x; xv[1] = va.y; xv[2] = va.z; xv[3] = va.w;
        xv[4] = vb.x; xv[5] = vb.y; xv[6] = vb.z; xv[7] = vb.w;

        // local zero-init scan: ls[j] = sum_{i<=j} a^(j-i) * w * xv[i]
        float ls[8];
        ls[0] = w * xv[0];
        #pragma unroll
        for (int j = 1; j < 8; ++j) ls[j] = fmaf(a, ls[j - 1], w * xv[j]);

        // wave-level Hillis-Steele affine scan of lane aggregates (ls[7]).
        float incl = ls[7];
        float t;
        t = __shfl_up(incl, 1);  if (lane >= 1)  incl = fmaf(m1,  t, incl);
        t = __shfl_up(incl, 2);  if (lane >= 2)  incl = fmaf(m2,  t, incl);
        t = __shfl_up(incl, 4);  if (lane >= 4)  incl = fmaf(m4,  t, incl);
        t = __shfl_up(incl, 8);  if (lane >= 8)  incl = fmaf(m8,  t, incl);
        t = __shfl_up(incl, 16); if (lane >= 16) incl = fmaf(m16, t, incl);
        t = __shfl_up(incl, 32); if (lane >= 32) incl = fmaf(m32, t, incl);

        float excl = __shfl_up(incl, 1);
        if (lane == 0) excl = 0.0f;

        // value entering this lane's first element: excl + a^(8*lane) * carry
        const float base = fmaf(p8l, c, excl);

        // y_j = ls[j] + a^(j+1) * base
        f32x4 oa, ob;
        oa.x = fmaf(apow[1], base, ls[0]);
        oa.y = fmaf(apow[2], base, ls[1]);
        oa.z = fmaf(apow[3], base, ls[2]);
        oa.w = fmaf(apow[4], base, ls[3]);
        ob.x = fmaf(apow[5], base, ls[4]);
        ob.y = fmaf(apow[6], base, ls[5]);
        ob.z = fmaf(apow[7], base, ls[6]);
        ob.w = fmaf(apow[8], base, ls[7]);

        // non-temporal: stream to HBM, don't allocate in L2/L3
        __builtin_nontemporal_store(oa, &orow[it * 128 + 2 * lane]);
        __builtin_nontemporal_store(ob, &orow[it * 128 + 2 * lane + 1]);

        // update carry for next chunk: y_last = incl_63 + a^512 * c
        float top = __shfl(incl, 63);
        c = fmaf(a512, c, top);
        va = na; vb = nb;
    }
}

extern "C" void kernel_launch(void* const* d_in, const int* in_sizes, int n_in,
                              void* d_out, int out_size, void* d_ws, size_t ws_size,
                              hipStream_t stream) {
    const float* x    = (const float*)d_in[0];
    const float* init = (const float*)d_in[1];
    const float* wt   = (const float*)d_in[2];
    float* out        = (float*)d_out;

    // 8192 rows, 1 wave (64 lanes) per row, 4 waves per 256-thread block
    dim3 grid(ROWS / 4), block(256);
    hipLaunchKernelGGL(ema_kernel, grid, block, 0, stream, x, init, wt, out);
}

// Round 5
// 44.953 us; speedup vs baseline: 1.6787x; 1.6787x over previous
//
#include <hip/hip_runtime.h>

// EMA scan: y_t = w*x_t + (1-w)*y_{t-1}, rows = B*C = 8192, T = 4096.
// fp32 in/out. One wave per row.
// R5: 4 floats/lane per chunk (16 chunks of 256 elems per row) so that EVERY
// load/store instruction covers a fully contiguous 1 KiB (4 lanes = one full
// 64B line). R4 showed the old 32B-stride pattern caused ~1.5x write
// amplification with nt stores (WRITE_SIZE 195 MB vs 134 MB logical) and 2x
// memory transactions generally. NT stores kept: with full-line coverage they
// stream cleanly and keep the 134 MB input L3-resident across replays.

#define ROWS 8192
#define T_LEN 4096
#define ITERS 16               // 4096 / 256

typedef float f32x4 __attribute__((ext_vector_type(4)));

__global__ __launch_bounds__(256) void ema_kernel(
    const float* __restrict__ x,     // [ROWS][T_LEN] fp32
    const float* __restrict__ init,  // [ROWS] fp32 (B,C,1 flattened)
    const float* __restrict__ wt,    // [1] fp32
    float* __restrict__ out)         // [ROWS][T_LEN] fp32
{
    const int lane = threadIdx.x & 63;
    const int wid  = threadIdx.x >> 6;
    const int row  = blockIdx.x * 4 + wid;

    float w = wt[0];
    w = fminf(fmaxf(w, 0.0f), 1.0f);
    const float a = 1.0f - w;

    // powers of a: apow[j] = a^j for j=0..4
    float apow[5];
    apow[0] = 1.0f;
    #pragma unroll
    for (int j = 1; j <= 4; ++j) apow[j] = apow[j - 1] * a;

    const float m1  = apow[4];   // a^4
    const float m2  = m1 * m1;   // a^8
    const float m4  = m2 * m2;   // a^16
    const float m8  = m4 * m4;   // a^32
    const float m16 = m8 * m8;   // a^64
    const float m32 = m16 * m16; // a^128
    const float a256 = m32 * m32;

    // per-lane power a^(4*lane) via binary exponentiation (branch-free)
    float p4l = 1.0f;
    {
        float b = m1; int e = lane;
        #pragma unroll
        for (int k = 0; k < 6; ++k) {
            p4l *= (e & 1) ? b : 1.0f;
            b *= b; e >>= 1;
        }
    }

    float c = init[row];   // carry y_0

    const f32x4* xrow = reinterpret_cast<const f32x4*>(x) + (size_t)row * (T_LEN / 4);
    f32x4*       orow = reinterpret_cast<f32x4*>(out)     + (size_t)row * (T_LEN / 4);

    f32x4 v = xrow[lane];   // prefetch chunk 0 (lane i -> contiguous float4 i)

    #pragma unroll
    for (int it = 0; it < ITERS; ++it) {
        f32x4 nv;
        if (it + 1 < ITERS) nv = xrow[(it + 1) * 64 + lane];

        // local zero-init scan over this lane's 4 elems
        float ls0 = w * v.x;
        float ls1 = fmaf(a, ls0, w * v.y);
        float ls2 = fmaf(a, ls1, w * v.z);
        float ls3 = fmaf(a, ls2, w * v.w);

        // wave-level Hillis-Steele affine scan of lane aggregates (ls3)
        float incl = ls3;
        float t;
        t = __shfl_up(incl, 1);  if (lane >= 1)  incl = fmaf(m1,  t, incl);
        t = __shfl_up(incl, 2);  if (lane >= 2)  incl = fmaf(m2,  t, incl);
        t = __shfl_up(incl, 4);  if (lane >= 4)  incl = fmaf(m4,  t, incl);
        t = __shfl_up(incl, 8);  if (lane >= 8)  incl = fmaf(m8,  t, incl);
        t = __shfl_up(incl, 16); if (lane >= 16) incl = fmaf(m16, t, incl);
        t = __shfl_up(incl, 32); if (lane >= 32) incl = fmaf(m32, t, incl);

        float excl = __shfl_up(incl, 1);
        if (lane == 0) excl = 0.0f;

        // value entering this lane's first element: excl + a^(4*lane) * carry
        const float base = fmaf(p4l, c, excl);

        f32x4 o;
        o.x = fmaf(apow[1], base, ls0);
        o.y = fmaf(apow[2], base, ls1);
        o.z = fmaf(apow[3], base, ls2);
        o.w = fmaf(apow[4], base, ls3);

        // non-temporal streaming store: contiguous 1 KiB per wave instruction
        __builtin_nontemporal_store(o, &orow[it * 64 + lane]);

        // carry for next chunk: y_last = incl_63 + a^256 * c
        float top = __shfl(incl, 63);
        c = fmaf(a256, c, top);
        v = nv;
    }
}

extern "C" void kernel_launch(void* const* d_in, const int* in_sizes, int n_in,
                              void* d_out, int out_size, void* d_ws, size_t ws_size,
                              hipStream_t stream) {
    const float* x    = (const float*)d_in[0];
    const float* init = (const float*)d_in[1];
    const float* wt   = (const float*)d_in[2];
    float* out        = (float*)d_out;

    // 8192 rows, 1 wave (64 lanes) per row, 4 waves per 256-thread block
    dim3 grid(ROWS / 4), block(256);
    hipLaunchKernelGGL(ema_kernel, grid, block, 0, stream, x, init, wt, out);
}